// Round 10
// baseline (91.189 us; speedup 1.0000x reference)
//
#include <hip/hip_runtime.h>

#define NBOX 4000
#define NPAD 4096
#define BATCH 8
#define WPR 64          // 64-bit words per suppression row
#define MAXK 300

typedef unsigned long long u64;

// Static device scratch (deterministic: every consulted value is rewritten
// each call; bits for rows >= nvalid are never consulted by the greedy).
__device__ u64 g_sup[BATCH][NPAD][WPR];            // ~16.8 MB full rows
__device__ u64 g_tile64[BATCH][64][64];            // diag word t of row 64t+r
__device__ u64 g_tileBx[BATCH][32][64];            // word 2s+1 of row 128s+r (r<64)
__device__ u64 g_colT[BATCH][66][64];              // transposed 64x64 diag blocks
__device__ u64 g_colTB[BATCH][33][64];             // transposed bank0->bank1 blocks
__device__ float4 g_sorted[BATCH][NPAD];           // 512 KB
__device__ int g_nvalid[BATCH];

// ---------------------------------------------------------------------------
// Kernel 1: per-batch stable LSD radix sort (6 passes x 4 bits). (unchanged,
// proven bit-exact) Key k = 0x3F800000 - bits(fg): valid => fg > 0.5 => k in
// (0, 0x800000), fits 24 bits. Invalid/pad k = 0xFFFFFF sorts last. Stable
// blocked radix preserves original-index order for ties (jnp.argsort).
// ---------------------------------------------------------------------------
#define SORT_T 256
#define EPT 16
#define HP 264
#define KIDX(n) ((((n) >> 4) * 17) + ((n) & 15))
#define KSZ (256 * 17)

__global__ __launch_bounds__(SORT_T) void sort_kernel(const float* __restrict__ props,
                                                      const float* __restrict__ scores) {
    const int b = blockIdx.x;
    const int tid = threadIdx.x;
    __shared__ unsigned int K0[KSZ], K1[KSZ];
    __shared__ unsigned short P0[KSZ], P1[KSZ];
    __shared__ unsigned short Hs[16 * HP];
    __shared__ unsigned int sWT[4];
    __shared__ int s_cnt;
    if (tid == 0) s_cnt = 0;
    __syncthreads();

    int localc = 0;
    for (int n = tid; n < NPAD; n += SORT_T) {
        unsigned int k = 0xFFFFFFu;
        if (n < NBOX) {
            const float2 sc = *reinterpret_cast<const float2*>(scores + ((size_t)b * NBOX + n) * 2);
            const float4 p  = *reinterpret_cast<const float4*>(props  + ((size_t)b * NBOX + n) * 4);
            const float fg = sc.y;
            const float w = __fsub_rn(p.z, p.x);
            const float h = __fsub_rn(p.w, p.y);
            if ((fg > 0.5f) && (w >= 16.0f) && (h >= 16.0f)) {
                k = 0x3F800000u - __float_as_uint(fg);
                localc++;
            }
        }
        K0[KIDX(n)] = k;
        P0[KIDX(n)] = (unsigned short)n;
    }
    for (int off = 32; off > 0; off >>= 1) localc += __shfl_down(localc, off);
    if ((tid & 63) == 0) atomicAdd(&s_cnt, localc);

    unsigned int kr[EPT];
    unsigned short pr[EPT];

    for (int pass = 0; pass < 6; ++pass) {
        const int shift = pass * 4;
        const unsigned int*   ksrc = (pass & 1) ? K1 : K0;
        unsigned int*         kdst = (pass & 1) ? K0 : K1;
        const unsigned short* psrc = (pass & 1) ? P1 : P0;
        unsigned short*       pdst = (pass & 1) ? P0 : P1;

        for (int hh = tid; hh < (16 * HP) / 2; hh += SORT_T)
            reinterpret_cast<unsigned int*>(Hs)[hh] = 0;
        __syncthreads();

        #pragma unroll
        for (int e = 0; e < EPT; ++e) {
            kr[e] = ksrc[tid * 17 + e];
            pr[e] = psrc[tid * 17 + e];
        }
        #pragma unroll
        for (int e = 0; e < EPT; ++e) {
            const unsigned int d = (kr[e] >> shift) & 15u;
            Hs[d * HP + tid]++;
        }
        __syncthreads();

        {
            const int d  = tid >> 4;
            const int t0 = (tid & 15) * 16;
            unsigned short* row = &Hs[d * HP];
            unsigned int sum = 0;
            #pragma unroll
            for (int e = 0; e < 16; ++e) {
                const unsigned int v = row[t0 + e];
                row[t0 + e] = (unsigned short)sum;
                sum += v;
            }
            unsigned int x = sum;
            #pragma unroll
            for (int off = 1; off < 64; off <<= 1) {
                const unsigned int y = __shfl_up(x, off);
                if ((tid & 63) >= off) x += y;
            }
            const int wid = tid >> 6;
            if ((tid & 63) == 63) sWT[wid] = x;
            __syncthreads();
            unsigned int base = x - sum;
            for (int w = 0; w < wid; ++w) base += sWT[w];
            #pragma unroll
            for (int e = 0; e < 16; ++e) row[t0 + e] += (unsigned short)base;
        }
        __syncthreads();

        #pragma unroll
        for (int e = 0; e < EPT; ++e) {
            const unsigned int d = (kr[e] >> shift) & 15u;
            const unsigned int pos = Hs[d * HP + tid]++;
            kdst[KIDX(pos)] = kr[e];
            pdst[KIDX(pos)] = pr[e];
        }
        __syncthreads();
    }

    const int nv = s_cnt;
    if (tid == 0) g_nvalid[b] = nv;
    for (int p = tid; p < NPAD; p += SORT_T) {
        if (p < nv) {
            const int idx = P0[KIDX(p)];
            g_sorted[b][p] = *reinterpret_cast<const float4*>(props + ((size_t)b * NBOX + idx) * 4);
        }
    }
}

// ---------------------------------------------------------------------------
// Kernel 2: suppression bitmask rows (triangular) + tile writes.
// lane c holds word c of row i after the ballot loop. Stores:
//   g_sup (full row, nontemporal — consumer is on another XCD),
//   g_tile64[t=i>>6] (diagonal word),
//   g_tileBx[s=i>>7] (word 2s+1 for bank0 rows r=i&127 < 64).
// ---------------------------------------------------------------------------
__global__ __launch_bounds__(64) void iou_kernel() {
    const int b = blockIdx.y;
    const int i = blockIdx.x;
    const int nv = g_nvalid[b];
    if (i >= nv) return;
    const int lane = threadIdx.x;
    const int c0 = i >> 6;
    const int W = (nv + 63) >> 6;

    const float4 bi = g_sorted[b][i];
    const float areai = __fmul_rn(__fsub_rn(bi.z, bi.x), __fsub_rn(bi.w, bi.y));

    u64 myword = 0ull;
    for (int c = c0; c < W; ++c) {
        const int j = (c << 6) + lane;
        bool pred = false;
        if (j < nv && j > i) {
            const float4 bj = g_sorted[b][j];
            const float areaj = __fmul_rn(__fsub_rn(bj.z, bj.x), __fsub_rn(bj.w, bj.y));
            const float xi1 = fmaxf(bi.x, bj.x);
            const float yi1 = fmaxf(bi.y, bj.y);
            const float xi2 = fminf(bi.z, bj.z);
            const float yi2 = fminf(bi.w, bj.w);
            const float iw = fmaxf(__fsub_rn(xi2, xi1), 0.0f);
            const float ih = fmaxf(__fsub_rn(yi2, yi1), 0.0f);
            const float inter = __fmul_rn(iw, ih);
            const float uni = __fsub_rn(__fadd_rn(areai, areaj), inter);
            pred = (inter / uni) >= 0.5f;
        }
        const u64 wd = __ballot(pred);
        if (lane == c) myword = wd;
    }
    __builtin_nontemporal_store(myword, &g_sup[b][i][lane]);
    if (lane == c0) g_tile64[b][c0][i & 63] = myword;
    const int sb = i >> 7;
    const int r  = i & 127;
    if (r < 64 && lane == 2 * sb + 1) g_tileBx[b][sb][r] = myword;
}

// ---------------------------------------------------------------------------
// Kernel 2b: transposes. Blocks 0..63: column j of 64x64 diag block t (bit r
// = M[64t+r][64t+j]). Blocks 64..95: column j of bank0->bank1 block s (bit k
// = M[128s+k][128s+64+j]). All-lane broadcast loads; fully parallel.
// ---------------------------------------------------------------------------
__global__ __launch_bounds__(64) void colT_kernel() {
    const int b = blockIdx.y;
    const int t = blockIdx.x;
    const int j = threadIdx.x;
    if (t < 64) {
        const u64* rw = &g_tile64[b][t][0];
        u64 col = 0ull;
        #pragma unroll
        for (int r = 0; r < 64; ++r)
            col |= ((rw[r] >> j) & 1ull) << r;
        g_colT[b][t][j] = col;
    } else {
        const int s = t - 64;
        const u64* rw = &g_tileBx[b][s][0];
        u64 col = 0ull;
        #pragma unroll
        for (int r = 0; r < 64; ++r)
            col |= ((rw[r] >> j) & 1ull) << r;
        g_colTB[b][s][j] = col;
    }
}

// ---------------------------------------------------------------------------
// Kernel 3: greedy scan, one wave per batch, 128-row SUPERBLOCKS with the
// R9-proven ballot greedy (lane-local VALU, no readlane broadcast on chain):
//   bank0: k=ctz(ballot(aliveA)); aliveA &= ~colT_even[k]; aliveB &= ~colTB[k]
//   bank1: k=ctz(ballot(aliveB)); aliveB &= ~colT_odd[k]
// ONE cross-SB OR round trip per 128 rows (14 steps vs R9's 28), and bank0's
// kept-row loads (<=32, deferred named regs) are ISSUED before bank1's greedy
// and consumed after — hiding most of that round trip under ~600 cy of VALU.
// ---------------------------------------------------------------------------
__device__ __forceinline__ int rdl(int v, int l) {
    return __builtin_amdgcn_readlane(v, l);
}
__device__ __forceinline__ unsigned int rdlu(unsigned int v, int l) {
    return (unsigned int)__builtin_amdgcn_readlane((int)v, l);
}
__device__ __forceinline__ u64 rdl64(u64 v, int l) {
    const unsigned lo = rdlu((unsigned)v, l);
    const unsigned hi = rdlu((unsigned)(v >> 32), l);
    return ((u64)hi << 32) | lo;
}

__global__ __launch_bounds__(64) void nms_kernel(float* __restrict__ out) {
    const int b = blockIdx.x;
    const int lane = threadIdx.x;
    int nv = g_nvalid[b];
    if (nv > NBOX) nv = NBOX;
    float4* outv = reinterpret_cast<float4*>(out) + (size_t)b * MAXK;
    const u64* supb = &g_sup[b][0][0];

    // zero-fill output up-front (off the critical chain)
    for (int s = lane; s < MAXK; s += 64)
        outv[s] = make_float4(0.0f, 0.0f, 0.0f, 0.0f);

    u64 removed = 0ull;                 // lane w holds removed word w
    int kept = 0;
    const int nsb = (nv + 127) >> 7;    // <= 32

    u64 cA = g_colT[b][0][lane];        // col lane of diag block 0 (bank0)
    u64 cB = g_colT[b][1][lane];        // col lane of diag block 1 (bank1)
    u64 cC = g_colTB[b][0][lane];       // col lane of bank0->bank1 block 0

    for (int s = 0; s < nsb && kept < MAXK; ++s) {
        const int base = s << 7;
        // prefetch next SB's columns (padded arrays; values discarded at end)
        const u64 nA = g_colT[b][2 * s + 2][lane];
        const u64 nB = g_colT[b][2 * s + 3][lane];
        const u64 nC = g_colTB[b][s + 1][lane];

        // incoming suppression words (4 readlanes, once per SB)
        const u64 w0 = rdl64(removed, 2 * s);
        const u64 w1 = rdl64(removed, 2 * s + 1);
        int aliveA = (int)((~w0 >> lane) & 1ull) & (int)(base + lane < nv);
        int aliveB = (int)((~w1 >> lane) & 1ull) & (int)(base + 64 + lane < nv);

        int m = 0;
        int myIdx0 = 0, myIdx1 = 0;     // lane t: t-th / (64+t)-th kept index
        const int cap = MAXK - kept;

        // bank 0 greedy (kept index m < 64 here; also projects onto bank1)
        u64 bal = __ballot(aliveA != 0);
        while (bal != 0ull && m < cap) {
            const int k = __builtin_ctzll(bal);
            if (lane == m) myIdx0 = base + k;
            aliveA &= (int)(~(cA >> k) & 1ull) & (int)(lane != k);
            aliveB &= (int)(~(cC >> k) & 1ull);
            ++m;
            bal = __ballot(aliveA != 0);
        }
        const int m0 = m;
        const bool doOR = (s + 1 < nsb);

        // deferred issue of bank0 kept rows' OR loads (<=32; consumed later)
        u64 va0=0,va1=0,va2=0,va3=0,va4=0,va5=0,va6=0,va7=0,
            va8=0,va9=0,va10=0,va11=0,va12=0,va13=0,va14=0,va15=0,
            va16=0,va17=0,va18=0,va19=0,va20=0,va21=0,va22=0,va23=0,
            va24=0,va25=0,va26=0,va27=0,va28=0,va29=0,va30=0,va31=0;
        int aCnt = 0;
        if (doOR && m0 > 0 && kept + m0 < MAXK) {
            aCnt = (m0 < 32) ? m0 : 32;
#define LA(j) { int tt = j; if (tt >= aCnt) tt = aCnt - 1;                      \
                const int it = rdl(myIdx0, tt);                                 \
                va##j = __builtin_nontemporal_load(&supb[(size_t)it * WPR + lane]); }
            LA(0)  LA(1)  LA(2)  LA(3)  LA(4)  LA(5)  LA(6)  LA(7)
            LA(8)  LA(9)  LA(10) LA(11) LA(12) LA(13) LA(14) LA(15)
            LA(16) LA(17) LA(18) LA(19) LA(20) LA(21) LA(22) LA(23)
            LA(24) LA(25) LA(26) LA(27) LA(28) LA(29) LA(30) LA(31)
#undef LA
        }

        // bank 1 greedy (runs while bank0's loads are in flight)
        bal = __ballot(aliveB != 0);
        while (bal != 0ull && m < cap) {
            const int k = __builtin_ctzll(bal);
            if (m < 64) { if (lane == m) myIdx0 = base + 64 + k; }
            else        { if (lane == m - 64) myIdx1 = base + 64 + k; }
            aliveB &= (int)(~(cB >> k) & 1ull) & (int)(lane != k);
            ++m;
            bal = __ballot(aliveB != 0);
        }

        if (m > 0) {
            const bool wantOR = doOR && (kept + m < MAXK);
            // consume deferred bank0 loads (waitcnt lands here, mostly hidden)
            if (wantOR && aCnt > 0) {
                const u64 o0 = ((va0 | va1) | (va2 | va3)) | ((va4 | va5) | (va6 | va7));
                const u64 o1 = ((va8 | va9) | (va10 | va11)) | ((va12 | va13) | (va14 | va15));
                const u64 o2 = ((va16 | va17) | (va18 | va19)) | ((va20 | va21) | (va22 | va23));
                const u64 o3 = ((va24 | va25) | (va26 | va27)) | ((va28 | va29) | (va30 | va31));
                removed |= (o0 | o1) | (o2 | o3);
            }
            // remaining rows (bank0 overflow past 32 + all bank1 kept)
            if (wantOR && m > aCnt) {
                for (int t = aCnt; t < m; t += 32) {
#define LDW(j) u64 v##j; {                                                      \
                        int tt = t + j; if (tt >= m) tt = m - 1;                \
                        const int it = (tt < 64) ? rdl(myIdx0, tt)              \
                                                 : rdl(myIdx1, tt - 64);        \
                        v##j = __builtin_nontemporal_load(                      \
                                   &supb[(size_t)it * WPR + lane]);             }
                    LDW(0)  LDW(1)  LDW(2)  LDW(3)  LDW(4)  LDW(5)  LDW(6)  LDW(7)
                    LDW(8)  LDW(9)  LDW(10) LDW(11) LDW(12) LDW(13) LDW(14) LDW(15)
                    LDW(16) LDW(17) LDW(18) LDW(19) LDW(20) LDW(21) LDW(22) LDW(23)
                    LDW(24) LDW(25) LDW(26) LDW(27) LDW(28) LDW(29) LDW(30) LDW(31)
#undef LDW
                    const u64 o0 = ((v0 | v1) | (v2 | v3)) | ((v4 | v5) | (v6 | v7));
                    const u64 o1 = ((v8 | v9) | (v10 | v11)) | ((v12 | v13) | (v14 | v15));
                    const u64 o2 = ((v16 | v17) | (v18 | v19)) | ((v20 | v21) | (v22 | v23));
                    const u64 o3 = ((v24 | v25) | (v26 | v27)) | ((v28 | v29) | (v30 | v31));
                    removed |= (o0 | o1) | (o2 | o3);
                }
            }
            // emit this SB's outputs (off-chain)
            {
                const int mm0 = (m < 64) ? m : 64;
                if (lane < mm0) outv[kept + lane] = g_sorted[b][myIdx0];
                if (m > 64 && lane < m - 64) outv[kept + 64 + lane] = g_sorted[b][myIdx1];
            }
            kept += m;
        }
        cA = nA; cB = nB; cC = nC;
    }
}

extern "C" void kernel_launch(void* const* d_in, const int* in_sizes, int n_in,
                              void* d_out, int out_size, void* d_ws, size_t ws_size,
                              hipStream_t stream) {
    const float* props  = (const float*)d_in[0];   // (8,4000,4) f32
    const float* scores = (const float*)d_in[1];   // (8,4000,2) f32
    float* out = (float*)d_out;                    // (8,300,4) f32

    sort_kernel<<<BATCH, SORT_T, 0, stream>>>(props, scores);
    iou_kernel<<<dim3(NBOX, BATCH), 64, 0, stream>>>();
    colT_kernel<<<dim3(96, BATCH), 64, 0, stream>>>();
    nms_kernel<<<BATCH, 64, 0, stream>>>(out);
}

// Round 12
// 62.842 us; speedup vs baseline: 1.4511x; 1.4511x over previous
//
#include <hip/hip_runtime.h>

#define NBOX 4000
#define NPAD 4096
#define BATCH 8
#define WPR 64          // 64-bit words per suppression row
#define MAXK 300

typedef unsigned long long u64;

// Static device scratch (deterministic: every consulted value is rewritten
// each call; bits/rows >= nvalid are masked out before use).
__device__ u64 g_sup[BATCH][NPAD][WPR];            // ~16.8 MB full rows
__device__ u64 g_tile64[BATCH][64][64];            // diag word t of row 64t+r
__device__ u64 g_colT[BATCH][65][64];              // transposed diag blocks
__device__ float4 g_sorted[BATCH][NPAD];           // 512 KB
__device__ int g_nvalid[BATCH];

// ---------------------------------------------------------------------------
// Kernel 1: per-batch stable LSD radix sort (6 passes x 4 bits). (unchanged,
// proven bit-exact) Key k = 0x3F800000 - bits(fg): valid => fg > 0.5 => k in
// (0, 0x800000), fits 24 bits. Invalid/pad k = 0xFFFFFF sorts last. Stable
// blocked radix preserves original-index order for ties (jnp.argsort).
// 8 blocks -> round-robin puts batch b on XCD b (matches iou/nms below).
// ---------------------------------------------------------------------------
#define SORT_T 256
#define EPT 16
#define HP 264
#define KIDX(n) ((((n) >> 4) * 17) + ((n) & 15))
#define KSZ (256 * 17)

__global__ __launch_bounds__(SORT_T) void sort_kernel(const float* __restrict__ props,
                                                      const float* __restrict__ scores) {
    const int b = blockIdx.x;
    const int tid = threadIdx.x;
    __shared__ unsigned int K0[KSZ], K1[KSZ];
    __shared__ unsigned short P0[KSZ], P1[KSZ];
    __shared__ unsigned short Hs[16 * HP];
    __shared__ unsigned int sWT[4];
    __shared__ int s_cnt;
    if (tid == 0) s_cnt = 0;
    __syncthreads();

    int localc = 0;
    for (int n = tid; n < NPAD; n += SORT_T) {
        unsigned int k = 0xFFFFFFu;
        if (n < NBOX) {
            const float2 sc = *reinterpret_cast<const float2*>(scores + ((size_t)b * NBOX + n) * 2);
            const float4 p  = *reinterpret_cast<const float4*>(props  + ((size_t)b * NBOX + n) * 4);
            const float fg = sc.y;
            const float w = __fsub_rn(p.z, p.x);
            const float h = __fsub_rn(p.w, p.y);
            if ((fg > 0.5f) && (w >= 16.0f) && (h >= 16.0f)) {
                k = 0x3F800000u - __float_as_uint(fg);
                localc++;
            }
        }
        K0[KIDX(n)] = k;
        P0[KIDX(n)] = (unsigned short)n;
    }
    for (int off = 32; off > 0; off >>= 1) localc += __shfl_down(localc, off);
    if ((tid & 63) == 0) atomicAdd(&s_cnt, localc);

    unsigned int kr[EPT];
    unsigned short pr[EPT];

    for (int pass = 0; pass < 6; ++pass) {
        const int shift = pass * 4;
        const unsigned int*   ksrc = (pass & 1) ? K1 : K0;
        unsigned int*         kdst = (pass & 1) ? K0 : K1;
        const unsigned short* psrc = (pass & 1) ? P1 : P0;
        unsigned short*       pdst = (pass & 1) ? P0 : P1;

        for (int hh = tid; hh < (16 * HP) / 2; hh += SORT_T)
            reinterpret_cast<unsigned int*>(Hs)[hh] = 0;
        __syncthreads();

        #pragma unroll
        for (int e = 0; e < EPT; ++e) {
            kr[e] = ksrc[tid * 17 + e];
            pr[e] = psrc[tid * 17 + e];
        }
        #pragma unroll
        for (int e = 0; e < EPT; ++e) {
            const unsigned int d = (kr[e] >> shift) & 15u;
            Hs[d * HP + tid]++;
        }
        __syncthreads();

        {
            const int d  = tid >> 4;
            const int t0 = (tid & 15) * 16;
            unsigned short* row = &Hs[d * HP];
            unsigned int sum = 0;
            #pragma unroll
            for (int e = 0; e < 16; ++e) {
                const unsigned int v = row[t0 + e];
                row[t0 + e] = (unsigned short)sum;
                sum += v;
            }
            unsigned int x = sum;
            #pragma unroll
            for (int off = 1; off < 64; off <<= 1) {
                const unsigned int y = __shfl_up(x, off);
                if ((tid & 63) >= off) x += y;
            }
            const int wid = tid >> 6;
            if ((tid & 63) == 63) sWT[wid] = x;
            __syncthreads();
            unsigned int base = x - sum;
            for (int w = 0; w < wid; ++w) base += sWT[w];
            #pragma unroll
            for (int e = 0; e < 16; ++e) row[t0 + e] += (unsigned short)base;
        }
        __syncthreads();

        #pragma unroll
        for (int e = 0; e < EPT; ++e) {
            const unsigned int d = (kr[e] >> shift) & 15u;
            const unsigned int pos = Hs[d * HP + tid]++;
            kdst[KIDX(pos)] = kr[e];
            pdst[KIDX(pos)] = pr[e];
        }
        __syncthreads();
    }

    const int nv = s_cnt;
    if (tid == 0) g_nvalid[b] = nv;
    for (int p = tid; p < NPAD; p += SORT_T) {
        if (p < nv) {
            const int idx = P0[KIDX(p)];
            g_sorted[b][p] = *reinterpret_cast<const float4*>(props + ((size_t)b * NBOX + idx) * 4);
        }
    }
}

// ---------------------------------------------------------------------------
// Kernel 2: suppression bitmask rows (triangular) + diagonal-word tile write.
// XCD-AFFINITY: 1D grid id = i*8 + b -> with round-robin dispatch, every
// block of batch b lands on XCD b, so g_sup/g_tile64 for batch b stay in
// XCD b's L2 — which is where nms block b runs. NORMAL stores (not nt):
// we now WANT L2 residency.
// ---------------------------------------------------------------------------
__global__ __launch_bounds__(64) void iou_kernel() {
    const int id = blockIdx.x;
    const int b = id & (BATCH - 1);
    const int i = id >> 3;
    const int nv = g_nvalid[b];
    if (i >= nv) return;
    const int lane = threadIdx.x;
    const int c0 = i >> 6;
    const int W = (nv + 63) >> 6;

    const float4 bi = g_sorted[b][i];
    const float areai = __fmul_rn(__fsub_rn(bi.z, bi.x), __fsub_rn(bi.w, bi.y));

    u64 myword = 0ull;
    for (int c = c0; c < W; ++c) {
        const int j = (c << 6) + lane;
        bool pred = false;
        if (j < nv && j > i) {
            const float4 bj = g_sorted[b][j];
            const float areaj = __fmul_rn(__fsub_rn(bj.z, bj.x), __fsub_rn(bj.w, bj.y));
            const float xi1 = fmaxf(bi.x, bj.x);
            const float yi1 = fmaxf(bi.y, bj.y);
            const float xi2 = fminf(bi.z, bj.z);
            const float yi2 = fminf(bi.w, bj.w);
            const float iw = fmaxf(__fsub_rn(xi2, xi1), 0.0f);
            const float ih = fmaxf(__fsub_rn(yi2, yi1), 0.0f);
            const float inter = __fmul_rn(iw, ih);
            const float uni = __fsub_rn(__fadd_rn(areai, areaj), inter);
            pred = (inter / uni) >= 0.5f;
        }
        const u64 wd = __ballot(pred);
        if (lane == c) myword = wd;
    }
    g_sup[b][i][lane] = myword;
    if (lane == c0) g_tile64[b][c0][i & 63] = myword;
}

// ---------------------------------------------------------------------------
// Kernel 2b: transpose each 64x64 diagonal block (column j, bit r =
// M[64t+r][64t+j]; strictly lower: bit r for r >= j is 0). Same 1D
// XCD-affinity indexing: id = t*8 + b.
// ---------------------------------------------------------------------------
__global__ __launch_bounds__(64) void colT_kernel() {
    const int id = blockIdx.x;
    const int b = id & (BATCH - 1);
    const int t = id >> 3;          // 0..63
    const int j = threadIdx.x;
    const u64* rw = &g_tile64[b][t][0];
    u64 col = 0ull;
    #pragma unroll
    for (int r = 0; r < 64; ++r)
        col |= ((rw[r] >> j) & 1ull) << r;
    g_colT[b][t][j] = col;
}

// ---------------------------------------------------------------------------
// Kernel 3: greedy scan, one wave per batch, JACOBI-FIXPOINT greedy:
// intra-block keep recurrence keep[j] = alive[j] & !OR_{k<j}(keep[k]&M[k][j])
// is strictly lower-triangular in colT (lane j holds column j), so iterating
//   keep <- alive & ((ballot(keep) & colT) == 0)
// converges to the UNIQUE fixpoint (= the serial greedy solution) in
// chain-depth+1 ballots (typ. 3-6) — replacing the ~11 serial kept-row
// iterations/block that were the measured invariant floor (R10 null result).
// Kept-index extraction: mbcnt rank + LDS scatter (emit, off-chain) and
// scalar ctz/clear (OR-load addresses). Cross-block OR: batched named-reg
// loads, now L2-local under the XCD-affinity launch.
// ---------------------------------------------------------------------------
__device__ __forceinline__ unsigned int rdlu(unsigned int v, int l) {
    return (unsigned int)__builtin_amdgcn_readlane((int)v, l);
}
__device__ __forceinline__ u64 rdl64(u64 v, int l) {
    const unsigned lo = rdlu((unsigned)v, l);
    const unsigned hi = rdlu((unsigned)(v >> 32), l);
    return ((u64)hi << 32) | lo;
}

__global__ __launch_bounds__(64) void nms_kernel(float* __restrict__ out) {
    const int b = blockIdx.x;
    const int lane = threadIdx.x;
    int nv = g_nvalid[b];
    if (nv > NBOX) nv = NBOX;
    float4* outv = reinterpret_cast<float4*>(out) + (size_t)b * MAXK;
    const u64* supb = &g_sup[b][0][0];
    __shared__ int sIdx[64];

    // zero-fill output up-front (off the critical chain)
    for (int s = lane; s < MAXK; s += 64)
        outv[s] = make_float4(0.0f, 0.0f, 0.0f, 0.0f);

    u64 removed = 0ull;                 // lane w holds removed word w
    int kept = 0;
    const int nblk = (nv + 63) >> 6;    // <= 63

    u64 colT = g_colT[b][0][lane];      // column lane of diagonal block 0

    for (int blk = 0; blk < nblk && kept < MAXK; ++blk) {
        const int base = blk << 6;
        // prefetch next block's transposed column (padded array, in-bounds)
        const u64 colT_n = g_colT[b][blk + 1][lane];

        // incoming suppression word for this block (2 readlanes, once/block)
        const u64 wv = rdl64(removed, blk);
        const int alive = (int)((~wv >> lane) & 1ull) & (int)(base + lane < nv);

        // Jacobi fixpoint (ballots only; no per-kept-row serial loop)
        u64 bal = __ballot(alive != 0);
        const unsigned cLo = (unsigned)colT, cHi = (unsigned)(colT >> 32);
        while (bal != 0ull) {
            const unsigned bLo = (unsigned)bal, bHi = (unsigned)(bal >> 32);
            const int sup = (((cLo & bLo) | (cHi & bHi)) != 0u);
            const u64 nb = __ballot((alive & (sup ^ 1)) != 0);
            if (nb == bal) break;
            bal = nb;
        }

        int m = __popcll(bal);
        const int cap = MAXK - kept;
        while (m > cap) {               // rare: only the final block
            bal &= ~(1ull << (63 - __builtin_clzll(bal)));
            --m;
        }

        if (m > 0) {
            // emit (off-chain): rank-compact kept indices via mbcnt + LDS
            unsigned rank = __builtin_amdgcn_mbcnt_lo((unsigned)bal, 0u);
            rank = __builtin_amdgcn_mbcnt_hi((unsigned)(bal >> 32), rank);
            if ((bal >> lane) & 1ull) sIdx[rank] = base + lane;
            const int myIdx = sIdx[lane];      // valid for lane < m
            if (lane < m) outv[kept + lane] = g_sorted[b][myIdx];

            // batched OR of kept rows' full suppression rows (scalar-extracted
            // addresses; loads L2-local under XCD affinity; ONE drain/group)
            if (kept + m < MAXK && blk + 1 < nblk) {
                u64 balT = bal;
                for (int t = 0; t < m; t += 32) {
#define LDW(j) u64 v##j = 0ull; {                                               \
                        if (t + j < m) {                                        \
                            const int it = base + __builtin_ctzll(balT);        \
                            balT &= balT - 1ull;                                \
                            v##j = supb[(size_t)it * WPR + lane];               \
                        } }
                    LDW(0)  LDW(1)  LDW(2)  LDW(3)  LDW(4)  LDW(5)  LDW(6)  LDW(7)
                    LDW(8)  LDW(9)  LDW(10) LDW(11) LDW(12) LDW(13) LDW(14) LDW(15)
                    LDW(16) LDW(17) LDW(18) LDW(19) LDW(20) LDW(21) LDW(22) LDW(23)
                    LDW(24) LDW(25) LDW(26) LDW(27) LDW(28) LDW(29) LDW(30) LDW(31)
#undef LDW
                    const u64 o0 = ((v0 | v1) | (v2 | v3)) | ((v4 | v5) | (v6 | v7));
                    const u64 o1 = ((v8 | v9) | (v10 | v11)) | ((v12 | v13) | (v14 | v15));
                    const u64 o2 = ((v16 | v17) | (v18 | v19)) | ((v20 | v21) | (v22 | v23));
                    const u64 o3 = ((v24 | v25) | (v26 | v27)) | ((v28 | v29) | (v30 | v31));
                    removed |= (o0 | o1) | (o2 | o3);
                }
            }
            kept += m;
        }
        colT = colT_n;
    }
}

extern "C" void kernel_launch(void* const* d_in, const int* in_sizes, int n_in,
                              void* d_out, int out_size, void* d_ws, size_t ws_size,
                              hipStream_t stream) {
    const float* props  = (const float*)d_in[0];   // (8,4000,4) f32
    const float* scores = (const float*)d_in[1];   // (8,4000,2) f32
    float* out = (float*)d_out;                    // (8,300,4) f32

    sort_kernel<<<BATCH, SORT_T, 0, stream>>>(props, scores);
    iou_kernel<<<NBOX * BATCH, 64, 0, stream>>>();        // id = i*8 + b
    colT_kernel<<<64 * BATCH, 64, 0, stream>>>();         // id = t*8 + b
    nms_kernel<<<BATCH, 64, 0, stream>>>(out);
}